// Round 1
// baseline (447.915 us; speedup 1.0000x reference)
//
#include <hip/hip_runtime.h>

typedef short short8 __attribute__((ext_vector_type(8)));
typedef float f32x4 __attribute__((ext_vector_type(4)));
typedef unsigned short u16;

namespace {
constexpr int NIMG = 16;
constexpr int CIN  = 256;
constexpr int HIMG = 56;
constexpr int WIMG = 56;
constexpr int KOUT = 256;
constexpr int PIX  = HIMG * WIMG;          // 3136
constexpr int HPAD = 58;                   // 56 + 2 halo
constexpr int NX   = NIMG * CIN * PIX;     // 12,845,056
constexpr int NGX  = (NX + 35) / 36;       // 356,808 groups (last has 4 elems)
constexpr int NWEL = KOUT * CIN * 9;       // 589,824
constexpr int NGW  = NWEL / 36;            // 16,384 (exact)
constexpr int XQ_HALVES = NIMG * HPAD * HPAD * CIN;  // 13,778,944 bf16 = 27.6 MB
}

// ---------------------------------------------------------------------------
// BFP quantize x (NCHW fp32) -> zero-padded NHWC bf16 [16][58][58][256].
// One thread per group of 36 consecutive flat elements. Group base is g*144
// bytes -> 16B aligned -> 9 float4 loads. bf16 store is exact (<=8 mantissa
// bits), so plain truncation of the fp32 bits is correct.
// ---------------------------------------------------------------------------
__global__ void quant_x_kernel(const float* __restrict__ x, u16* __restrict__ xq) {
    int g = blockIdx.x * 256 + threadIdx.x;
    if (g >= NGX) return;
    int base = g * 36;
    int cnt = NX - base; if (cnt > 36) cnt = 36;
    float v[36];
    if (cnt == 36) {
        const float4* p4 = (const float4*)(x + base);
#pragma unroll
        for (int j = 0; j < 9; j++) {
            float4 t = p4[j];
            v[4*j+0] = t.x; v[4*j+1] = t.y; v[4*j+2] = t.z; v[4*j+3] = t.w;
        }
    } else {
        for (int j = 0; j < 36; j++) v[j] = (j < cnt) ? x[base + j] : 0.f;
    }
    float ma = 0.f;
#pragma unroll
    for (int j = 0; j < 36; j++) ma = fmaxf(ma, fabsf(v[j]));
    float scale, rinv;
    if (ma == 0.f) { scale = 0.f; rinv = 0.f; }
    else {
        float e = floorf(log2f(ma));     // matches floor(log2(maxabs)) of ref
        scale = exp2f(e - 7.f);
        rinv  = exp2f(7.f - e);          // exact pow2: x*rinv == x/scale
    }
    // decode starting NCHW coords of flat index `base`
    int nimg = base / (CIN * PIX);
    int rem  = base % (CIN * PIX);
    int c = rem / PIX;
    int p = rem % PIX;
    int h = p / WIMG;
    int w = p % WIMG;
    for (int j = 0; j < cnt; j++) {
        float q = rintf(v[j] * rinv);               // round-half-to-even == jnp.round
        q = fminf(fmaxf(q, -128.f), 127.f) * scale; // clip then rescale
        int addr = ((nimg * HPAD + h + 1) * HPAD + (w + 1)) * CIN + c;
        xq[addr] = (u16)(__float_as_uint(q) >> 16); // exact bf16
        w++;
        if (w == WIMG) { w = 0; h++; if (h == HIMG) { h = 0; c++; if (c == CIN) { c = 0; nimg++; } } }
    }
}

// ---------------------------------------------------------------------------
// BFP quantize weight (OIHW fp32) -> bf16 [rs=9][kout=256][cin=256].
// Groups (36) tile exactly: 2304 per out-channel = 64 groups; each group is
// 4 input channels x 9 taps of one k.
// ---------------------------------------------------------------------------
__global__ void quant_w_kernel(const float* __restrict__ wsrc, u16* __restrict__ wt) {
    int g = blockIdx.x * 256 + threadIdx.x;
    if (g >= NGW) return;
    int base = g * 36;
    float v[36];
    const float4* p4 = (const float4*)(wsrc + base);
#pragma unroll
    for (int j = 0; j < 9; j++) {
        float4 t = p4[j];
        v[4*j+0] = t.x; v[4*j+1] = t.y; v[4*j+2] = t.z; v[4*j+3] = t.w;
    }
    float ma = 0.f;
#pragma unroll
    for (int j = 0; j < 36; j++) ma = fmaxf(ma, fabsf(v[j]));
    float scale, rinv;
    if (ma == 0.f) { scale = 0.f; rinv = 0.f; }
    else {
        float e = floorf(log2f(ma));
        scale = exp2f(e - 7.f);
        rinv  = exp2f(7.f - e);
    }
    int k  = g >> 6;            // g/64
    int c0 = (g & 63) * 4;
#pragma unroll
    for (int j = 0; j < 36; j++) {
        float q = rintf(v[j] * rinv);
        q = fminf(fmaxf(q, -128.f), 127.f) * scale;
        int c  = c0 + j / 9;
        int rs = j % 9;
        wt[(rs * KOUT + k) * CIN + c] = (u16)(__float_as_uint(q) >> 16);
    }
}

// ---------------------------------------------------------------------------
// Implicit-GEMM conv via bf16 MFMA 16x16x32.
//   GEMM: M = outch (A = weights [rs][k][c]), N = spatial (B = acts NHWC),
//         K = cin, looped over 9 filter taps. C-layout col=lane&15 -> spatial
//         -> coalesced NCHW fp32 stores.
// Block tile 128(outch) x 128(spatial), 4 waves of 64x64, BK=32.
// LDS chunked layout [kchunk(4)][row(128)][8 halves]: every ds op is an
// aligned b128; staging writes are lane-linear (offset = 16*tid) -> conflict
// free.  3136 % 128 != 0, so spatial tiles may straddle two images: decode
// n/p per-lane.
// ---------------------------------------------------------------------------
__global__ __launch_bounds__(256) void conv_kernel(
        const u16* __restrict__ xq, const u16* __restrict__ wt,
        const float* __restrict__ bias, float* __restrict__ out) {
    __shared__ u16 lA[4096];   // 4 chunks * 128 rows * 8
    __shared__ u16 lB[4096];

    const int tid  = threadIdx.x;
    const int lane = tid & 63;
    const int wv   = tid >> 6;
    const int k0   = blockIdx.y * 128;   // outch base
    const int m0   = blockIdx.x * 128;   // flat spatial base

    // ---- staging source addresses (thread t: chunk=wv, rows 2*(t&63), +1)
    const int r0 = (tid & 63) * 2;
    const u16* wA0 = wt + (k0 + r0) * CIN + wv * 8;
    const u16* wA1 = wA0 + CIN;

    int sp0 = m0 + r0;
    int n0 = sp0 / PIX, pp0 = sp0 % PIX;
    int h0 = pp0 / WIMG, w0 = pp0 % WIMG;
    int sp1 = sp0 + 1;
    int n1 = sp1 / PIX, pp1 = sp1 % PIX;
    int h1 = pp1 / WIMG, w1 = pp1 % WIMG;
    const u16* xB0 = xq + ((n0 * HPAD + h0 + 1) * HPAD + (w0 + 1)) * CIN + wv * 8;
    const u16* xB1 = xq + ((n1 * HPAD + h1 + 1) * HPAD + (w1 + 1)) * CIN + wv * 8;

    // ---- fragment read pointers
    const int frow = lane & 15;
    const int fkk  = lane >> 4;
    const u16* fA = lA + fkk * 1024 + ((wv >> 1) * 64 + frow) * 8;
    const u16* fB = lB + fkk * 1024 + ((wv & 1) * 64 + frow) * 8;

    f32x4 acc[4][4] = {};

    for (int rs = 0; rs < 9; rs++) {
        const int dy = rs / 3 - 1, dx = rs % 3 - 1;
        const int xoff = (dy * HPAD + dx) * CIN;
        const int woff = rs * KOUT * CIN;
        for (int c0 = 0; c0 < CIN; c0 += 32) {
            short8 a0 = *(const short8*)(wA0 + woff + c0);
            short8 a1 = *(const short8*)(wA1 + woff + c0);
            short8 b0 = *(const short8*)(xB0 + xoff + c0);
            short8 b1 = *(const short8*)(xB1 + xoff + c0);
            __syncthreads();                       // prev iter's frag reads done
            *(short8*)(lA + tid * 16)     = a0;
            *(short8*)(lA + tid * 16 + 8) = a1;
            *(short8*)(lB + tid * 16)     = b0;
            *(short8*)(lB + tid * 16 + 8) = b1;
            __syncthreads();
            short8 af[4], bf[4];
#pragma unroll
            for (int i = 0; i < 4; i++) af[i] = *(const short8*)(fA + i * 128);
#pragma unroll
            for (int j = 0; j < 4; j++) bf[j] = *(const short8*)(fB + j * 128);
#pragma unroll
            for (int i = 0; i < 4; i++)
#pragma unroll
                for (int j = 0; j < 4; j++)
                    acc[i][j] = __builtin_amdgcn_mfma_f32_16x16x32_bf16(
                        af[i], bf[j], acc[i][j], 0, 0, 0);
        }
    }

    // ---- epilogue: D row = outch (quad*4+reg), col = spatial (lane&15)
    const int kbase = k0 + (wv >> 1) * 64 + fkk * 4;
    const int mbase = m0 + (wv & 1) * 64 + frow;
#pragma unroll
    for (int j = 0; j < 4; j++) {
        int sp = mbase + j * 16;
        int ni = sp / PIX, pq = sp % PIX;   // 16-aligned subtiles never straddle images mid-group
        float* ob = out + ni * KOUT * PIX + pq;
#pragma unroll
        for (int i = 0; i < 4; i++) {
            int kch = kbase + i * 16;
#pragma unroll
            for (int r = 0; r < 4; r++)
                ob[(kch + r) * PIX] = acc[i][j][r] + bias[kch + r];
        }
    }
}

// ---------------------------------------------------------------------------
extern "C" void kernel_launch(void* const* d_in, const int* in_sizes, int n_in,
                              void* d_out, int out_size, void* d_ws, size_t ws_size,
                              hipStream_t stream) {
    const float* x   = (const float*)d_in[0];
    const float* wgt = (const float*)d_in[1];
    const float* bs  = (const float*)d_in[2];
    float* out = (float*)d_out;

    u16* xq = (u16*)d_ws;                 // 27,557,888 B padded NHWC bf16
    u16* wt = xq + XQ_HALVES;             // 1,179,648 B  [rs][k][c] bf16
    // total ws use ~28.7 MB

    // zero the padded activation buffer (d_ws is re-poisoned each launch)
    hipMemsetAsync(xq, 0, (size_t)XQ_HALVES * 2, stream);

    quant_x_kernel<<<(NGX + 255) / 256, 256, 0, stream>>>(x, xq);
    quant_w_kernel<<<(NGW + 255) / 256, 256, 0, stream>>>(wgt, wt);
    conv_kernel<<<dim3(50176 / 128, 2), 256, 0, stream>>>(xq, wt, bs, out);
}

// Round 2
// 283.532 us; speedup vs baseline: 1.5798x; 1.5798x over previous
//
#include <hip/hip_runtime.h>

typedef short short8 __attribute__((ext_vector_type(8)));
typedef float f32x4 __attribute__((ext_vector_type(4)));
typedef unsigned short u16;

namespace {
constexpr int NIMG = 16;
constexpr int CIN  = 256;
constexpr int HIMG = 56;
constexpr int WIMG = 56;
constexpr int KOUT = 256;
constexpr int PIX  = HIMG * WIMG;          // 3136
constexpr int HPAD = 58;                   // 56 + 2 halo
constexpr int NX   = NIMG * CIN * PIX;     // 12,845,056
constexpr int NGX  = (NX + 35) / 36;       // 356,808 groups (last has 4 elems)
constexpr int NWEL = KOUT * CIN * 9;       // 589,824
constexpr int NGW  = NWEL / 36;            // 16,384 (exact)
constexpr int XQ_HALVES = NIMG * HPAD * HPAD * CIN;  // 13,778,944 bf16 = 27.6 MB
}

// ---------------------------------------------------------------------------
// Phase 1: BFP quantize x (NCHW fp32) -> NCHW bf16 (same flat order).
// One thread per 36-group; reads 9 float4 (144B) and writes 72B, both fully
// coalesced. bf16 is exact for 8-bit BFP mantissas.
// ---------------------------------------------------------------------------
__global__ void quant_x_nchw(const float* __restrict__ x, u16* __restrict__ qn) {
    int g = blockIdx.x * 256 + threadIdx.x;
    if (g >= NGX) return;
    int base = g * 36;
    int cnt = NX - base; if (cnt > 36) cnt = 36;
    float v[36];
    if (cnt == 36) {
        const float4* p4 = (const float4*)(x + base);
#pragma unroll
        for (int j = 0; j < 9; j++) {
            float4 t = p4[j];
            v[4*j+0] = t.x; v[4*j+1] = t.y; v[4*j+2] = t.z; v[4*j+3] = t.w;
        }
    } else {
        for (int j = 0; j < 36; j++) v[j] = (j < cnt) ? x[base + j] : 0.f;
    }
    float ma = 0.f;
#pragma unroll
    for (int j = 0; j < 36; j++) ma = fmaxf(ma, fabsf(v[j]));
    float scale = 0.f, rinv = 0.f;
    if (ma != 0.f) {
        float e = floorf(log2f(ma));
        scale = exp2f(e - 7.f);
        rinv  = exp2f(7.f - e);
    }
    u16 qq[36];
#pragma unroll
    for (int j = 0; j < 36; j++) {
        float q = rintf(v[j] * rinv);                 // round-half-even == jnp.round
        q = fminf(fmaxf(q, -128.f), 127.f) * scale;
        qq[j] = (u16)(__float_as_uint(q) >> 16);      // exact bf16
    }
    if (cnt == 36) {
        uint2* o = (uint2*)(qn + base);               // base*2 bytes, 8B aligned
#pragma unroll
        for (int k = 0; k < 9; k++) {
            uint lo = (uint)qq[4*k]   | ((uint)qq[4*k+1] << 16);
            uint hi = (uint)qq[4*k+2] | ((uint)qq[4*k+3] << 16);
            o[k] = make_uint2(lo, hi);
        }
    } else {
        for (int j = 0; j < cnt; j++) qn[base + j] = qq[j];
    }
}

// ---------------------------------------------------------------------------
// Phase 2: LDS-tiled transpose NCHW bf16 -> zero-padded NHWC bf16.
// Tile = 64 channels x 64 pixels. Global reads: short8 per lane, contiguous
// 128B per channel row. Global writes: each pixel's 64-channel segment is
// 128B contiguous. LDS held as u32 stride 65 -> worst aliasing 2-way (free).
// PIX = 3136 = 49*64 exactly, so tiles never straddle channel boundaries.
// ---------------------------------------------------------------------------
__global__ __launch_bounds__(256) void transpose_x(
        const u16* __restrict__ qn, u16* __restrict__ xq) {
    __shared__ uint tile[64][65];
    const int t  = threadIdx.x;
    const int p0 = blockIdx.x * 64;
    const int c0 = blockIdx.y * 64;
    const int n  = blockIdx.z;

    const int jc  = t & 7;          // pixel chunk (8 px)
    const int ci0 = t >> 3;         // channel row 0..31
#pragma unroll
    for (int l = 0; l < 2; l++) {
        int ci = ci0 + 32 * l;
        const short8 vv = *(const short8*)(qn + (size_t)n * CIN * PIX
                                           + (c0 + ci) * PIX + p0 + jc * 8);
#pragma unroll
        for (int j = 0; j < 8; j++)
            tile[ci][jc * 8 + j] = (uint)(u16)vv[j];
    }
    __syncthreads();

    const int pi    = t >> 2;        // output pixel 0..63
    const int cbase = (t & 3) * 16;  // 16 channels per thread
    const int p = p0 + pi;
    const int h = p / WIMG, w = p % WIMG;
    u16* ob = xq + ((size_t)(n * HPAD + h + 1) * HPAD + (w + 1)) * CIN + c0 + cbase;
#pragma unroll
    for (int s = 0; s < 2; s++) {
        short8 o;
#pragma unroll
        for (int j = 0; j < 8; j++)
            o[j] = (short)tile[cbase + s * 8 + j][pi];
        *(short8*)(ob + s * 8) = o;
    }
}

// ---------------------------------------------------------------------------
// Zero only the halo ring of the padded NHWC buffer (1.9 MB vs 27.6 MB memset).
// 228 halo pixels per image; 32 threads (uint4 = 8 ch) per pixel.
// ---------------------------------------------------------------------------
__global__ void zero_halo(u16* __restrict__ xq) {
    int t = blockIdx.x * 256 + threadIdx.x;          // 16*228*32 = 116,736
    if (t >= NIMG * 228 * 32) return;
    int chunk = t & 31;
    int ps = t >> 5;
    int n = ps / 228, s = ps % 228;
    int h, w;
    if (s < 58)       { h = 0;  w = s; }
    else if (s < 116) { h = 57; w = s - 58; }
    else { int r = s - 116; h = 1 + (r >> 1); w = (r & 1) * 57; }
    size_t addr = ((size_t)(n * HPAD + h) * HPAD + w) * CIN + chunk * 8;
    *(uint4*)(xq + addr) = make_uint4(0, 0, 0, 0);
}

// ---------------------------------------------------------------------------
// BFP quantize weight (OIHW fp32) -> bf16 [rs=9][kout=256][cin=256].
// ---------------------------------------------------------------------------
__global__ void quant_w_kernel(const float* __restrict__ wsrc, u16* __restrict__ wt) {
    int g = blockIdx.x * 256 + threadIdx.x;
    if (g >= NGW) return;
    int base = g * 36;
    float v[36];
    const float4* p4 = (const float4*)(wsrc + base);
#pragma unroll
    for (int j = 0; j < 9; j++) {
        float4 t = p4[j];
        v[4*j+0] = t.x; v[4*j+1] = t.y; v[4*j+2] = t.z; v[4*j+3] = t.w;
    }
    float ma = 0.f;
#pragma unroll
    for (int j = 0; j < 36; j++) ma = fmaxf(ma, fabsf(v[j]));
    float scale = 0.f, rinv = 0.f;
    if (ma != 0.f) {
        float e = floorf(log2f(ma));
        scale = exp2f(e - 7.f);
        rinv  = exp2f(7.f - e);
    }
    int k  = g >> 6;
    int c0 = (g & 63) * 4;
#pragma unroll
    for (int j = 0; j < 36; j++) {
        float q = rintf(v[j] * rinv);
        q = fminf(fmaxf(q, -128.f), 127.f) * scale;
        int c  = c0 + j / 9;
        int rs = j % 9;
        wt[(rs * KOUT + k) * CIN + c] = (u16)(__float_as_uint(q) >> 16);
    }
}

// ---------------------------------------------------------------------------
// Implicit-GEMM conv via bf16 MFMA 16x16x32 (unchanged from R1).
// ---------------------------------------------------------------------------
__global__ __launch_bounds__(256) void conv_kernel(
        const u16* __restrict__ xq, const u16* __restrict__ wt,
        const float* __restrict__ bias, float* __restrict__ out) {
    __shared__ u16 lA[4096];
    __shared__ u16 lB[4096];

    const int tid  = threadIdx.x;
    const int lane = tid & 63;
    const int wv   = tid >> 6;
    const int k0   = blockIdx.y * 128;
    const int m0   = blockIdx.x * 128;

    const int r0 = (tid & 63) * 2;
    const u16* wA0 = wt + (k0 + r0) * CIN + wv * 8;
    const u16* wA1 = wA0 + CIN;

    int sp0 = m0 + r0;
    int n0 = sp0 / PIX, pp0 = sp0 % PIX;
    int h0 = pp0 / WIMG, w0 = pp0 % WIMG;
    int sp1 = sp0 + 1;
    int n1 = sp1 / PIX, pp1 = sp1 % PIX;
    int h1 = pp1 / WIMG, w1 = pp1 % WIMG;
    const u16* xB0 = xq + ((n0 * HPAD + h0 + 1) * HPAD + (w0 + 1)) * CIN + wv * 8;
    const u16* xB1 = xq + ((n1 * HPAD + h1 + 1) * HPAD + (w1 + 1)) * CIN + wv * 8;

    const int frow = lane & 15;
    const int fkk  = lane >> 4;
    const u16* fA = lA + fkk * 1024 + ((wv >> 1) * 64 + frow) * 8;
    const u16* fB = lB + fkk * 1024 + ((wv & 1) * 64 + frow) * 8;

    f32x4 acc[4][4] = {};

    for (int rs = 0; rs < 9; rs++) {
        const int dy = rs / 3 - 1, dx = rs % 3 - 1;
        const int xoff = (dy * HPAD + dx) * CIN;
        const int woff = rs * KOUT * CIN;
        for (int c0 = 0; c0 < CIN; c0 += 32) {
            short8 a0 = *(const short8*)(wA0 + woff + c0);
            short8 a1 = *(const short8*)(wA1 + woff + c0);
            short8 b0 = *(const short8*)(xB0 + xoff + c0);
            short8 b1 = *(const short8*)(xB1 + xoff + c0);
            __syncthreads();
            *(short8*)(lA + tid * 16)     = a0;
            *(short8*)(lA + tid * 16 + 8) = a1;
            *(short8*)(lB + tid * 16)     = b0;
            *(short8*)(lB + tid * 16 + 8) = b1;
            __syncthreads();
            short8 af[4], bf[4];
#pragma unroll
            for (int i = 0; i < 4; i++) af[i] = *(const short8*)(fA + i * 128);
#pragma unroll
            for (int j = 0; j < 4; j++) bf[j] = *(const short8*)(fB + j * 128);
#pragma unroll
            for (int i = 0; i < 4; i++)
#pragma unroll
                for (int j = 0; j < 4; j++)
                    acc[i][j] = __builtin_amdgcn_mfma_f32_16x16x32_bf16(
                        af[i], bf[j], acc[i][j], 0, 0, 0);
        }
    }

    const int kbase = k0 + (wv >> 1) * 64 + fkk * 4;
    const int mbase = m0 + (wv & 1) * 64 + frow;
#pragma unroll
    for (int j = 0; j < 4; j++) {
        int sp = mbase + j * 16;
        int ni = sp / PIX, pq = sp % PIX;
        float* ob = out + ni * KOUT * PIX + pq;
#pragma unroll
        for (int i = 0; i < 4; i++) {
            int kch = kbase + i * 16;
#pragma unroll
            for (int r = 0; r < 4; r++)
                ob[(kch + r) * PIX] = acc[i][j][r] + bias[kch + r];
        }
    }
}

// ---------------------------------------------------------------------------
extern "C" void kernel_launch(void* const* d_in, const int* in_sizes, int n_in,
                              void* d_out, int out_size, void* d_ws, size_t ws_size,
                              hipStream_t stream) {
    const float* x   = (const float*)d_in[0];
    const float* wgt = (const float*)d_in[1];
    const float* bs  = (const float*)d_in[2];
    float* out = (float*)d_out;

    u16* xq = (u16*)d_ws;                 // 27.6 MB padded NHWC bf16
    u16* wt = xq + XQ_HALVES;             // 1.2 MB  [rs][k][c] bf16
    u16* qn = wt + NWEL;                  // 25.7 MB NCHW bf16 intermediate
    // total ws use ~54.4 MB

    quant_x_nchw<<<(NGX + 255) / 256, 256, 0, stream>>>(x, qn);
    zero_halo<<<(NIMG * 228 * 32 + 255) / 256, 256, 0, stream>>>(xq);
    quant_w_kernel<<<(NGW + 255) / 256, 256, 0, stream>>>(wgt, wt);
    transpose_x<<<dim3(PIX / 64, CIN / 64, NIMG), 256, 0, stream>>>(qn, xq);
    conv_kernel<<<dim3(50176 / 128, 2), 256, 0, stream>>>(xq, wt, bs, out);
}

// Round 3
// 222.264 us; speedup vs baseline: 2.0152x; 1.2757x over previous
//
#include <hip/hip_runtime.h>

typedef short short8 __attribute__((ext_vector_type(8)));
typedef float f32x4 __attribute__((ext_vector_type(4)));
typedef unsigned short u16;
typedef __attribute__((address_space(3))) unsigned lds_u32_t;
typedef __attribute__((address_space(1))) const unsigned glb_u32_t;

namespace {
constexpr int NIMG = 16;
constexpr int CIN  = 256;
constexpr int HIMG = 56;
constexpr int WIMG = 56;
constexpr int KOUT = 256;
constexpr int PIX  = HIMG * WIMG;          // 3136
constexpr int HPAD = 58;
constexpr int PP   = HPAD * HPAD;          // 3364 padded pixels per image
constexpr int TILES = 26;                  // ceil(3246/128) -> 26*128 = 3328
constexpr int NX   = NIMG * CIN * PIX;     // 12,845,056
constexpr int NGX  = (NX + 35) / 36;       // 356,808
constexpr int NWEL = KOUT * CIN * 9;       // 589,824
constexpr int NGW  = NWEL / 36;            // 16,384
constexpr int XQ_HALVES = NIMG * 32 * PP * 8;   // 13,778,944
constexpr int MAXB = XQ_HALVES - 8;        // clamp for tail gather lanes
constexpr int NHALO = NIMG * 32 * 228;     // 116,736 halo chunk-stores
}

// ---------------------------------------------------------------------------
// Phase 1: BFP quantize x (NCHW fp32) -> NCHW bf16, fully coalesced.
// ---------------------------------------------------------------------------
__global__ void quant_x_nchw(const float* __restrict__ x, u16* __restrict__ qn) {
    int g = blockIdx.x * 256 + threadIdx.x;
    if (g >= NGX) return;
    int base = g * 36;
    int cnt = NX - base; if (cnt > 36) cnt = 36;
    float v[36];
    if (cnt == 36) {
        const float4* p4 = (const float4*)(x + base);
#pragma unroll
        for (int j = 0; j < 9; j++) {
            float4 t = p4[j];
            v[4*j+0] = t.x; v[4*j+1] = t.y; v[4*j+2] = t.z; v[4*j+3] = t.w;
        }
    } else {
        for (int j = 0; j < 36; j++) v[j] = (j < cnt) ? x[base + j] : 0.f;
    }
    float ma = 0.f;
#pragma unroll
    for (int j = 0; j < 36; j++) ma = fmaxf(ma, fabsf(v[j]));
    float scale = 0.f, rinv = 0.f;
    if (ma != 0.f) {
        float e = floorf(log2f(ma));
        scale = exp2f(e - 7.f);
        rinv  = exp2f(7.f - e);
    }
    u16 qq[36];
#pragma unroll
    for (int j = 0; j < 36; j++) {
        float q = rintf(v[j] * rinv);                 // round-half-even
        q = fminf(fmaxf(q, -128.f), 127.f) * scale;
        qq[j] = (u16)(__float_as_uint(q) >> 16);      // exact bf16
    }
    if (cnt == 36) {
        uint2* o = (uint2*)(qn + base);
#pragma unroll
        for (int k = 0; k < 9; k++)
            o[k] = make_uint2((uint)qq[4*k] | ((uint)qq[4*k+1] << 16),
                              (uint)qq[4*k+2] | ((uint)qq[4*k+3] << 16));
    } else {
        for (int j = 0; j < cnt; j++) qn[base + j] = qq[j];
    }
}

// ---------------------------------------------------------------------------
// Phase 2: LDS-tiled scatter NCHW bf16 -> channel-chunked padded layout
//   xq2[n][cc=c/8][pp=ph*58+pw][8], interior only (pp=(i+1)*58+(j+1)).
// ---------------------------------------------------------------------------
__global__ __launch_bounds__(256) void transpose_x(
        const u16* __restrict__ qn, u16* __restrict__ xq2) {
    __shared__ uint tile[64][65];
    const int t  = threadIdx.x;
    const int p0 = blockIdx.x * 64;
    const int c0 = blockIdx.y * 64;
    const int n  = blockIdx.z;

    const int jc  = t & 7;
    const int ci0 = t >> 3;
#pragma unroll
    for (int l = 0; l < 2; l++) {
        int ci = ci0 + 32 * l;
        const short8 vv = *(const short8*)(qn + (size_t)n * CIN * PIX
                                           + (c0 + ci) * PIX + p0 + jc * 8);
#pragma unroll
        for (int j = 0; j < 8; j++)
            tile[ci][jc * 8 + j] = (uint)(u16)vv[j];
    }
    __syncthreads();

    const int pi  = t & 63;
    const int cc0 = t >> 6;          // 0..3
    const int p = p0 + pi;
    const int i = p / WIMG, j = p % WIMG;
    const int pp = (i + 1) * HPAD + (j + 1);
#pragma unroll
    for (int s = 0; s < 2; s++) {
        int cc = cc0 + 4 * s;        // 0..7 within this 64-ch tile
        short8 o;
#pragma unroll
        for (int q = 0; q < 8; q++)
            o[q] = (short)tile[cc * 8 + q][pi];
        *(short8*)(xq2 + ((size_t)(n * 32 + (c0 >> 3) + cc) * PP + pp) * 8) = o;
    }
}

// ---------------------------------------------------------------------------
// Fused: quantize weights -> wt2[rs][cs][kc][kout][8]  (blocks 0..63)
//        zero halo ring of xq2 (chunked layout)        (blocks 64..519)
// ---------------------------------------------------------------------------
__global__ void quant_w_halo(const float* __restrict__ wsrc,
                             u16* __restrict__ wt2, u16* __restrict__ xq2) {
    int b = blockIdx.x;
    if (b < 64) {
        int g = b * 256 + threadIdx.x;          // < 16384 always
        int base = g * 36;
        float v[36];
        const float4* p4 = (const float4*)(wsrc + base);
#pragma unroll
        for (int j = 0; j < 9; j++) {
            float4 t = p4[j];
            v[4*j+0] = t.x; v[4*j+1] = t.y; v[4*j+2] = t.z; v[4*j+3] = t.w;
        }
        float ma = 0.f;
#pragma unroll
        for (int j = 0; j < 36; j++) ma = fmaxf(ma, fabsf(v[j]));
        float scale = 0.f, rinv = 0.f;
        if (ma != 0.f) {
            float e = floorf(log2f(ma));
            scale = exp2f(e - 7.f);
            rinv  = exp2f(7.f - e);
        }
        int k  = g >> 6;
        int c0 = (g & 63) * 4;
#pragma unroll
        for (int j = 0; j < 36; j++) {
            float q = rintf(v[j] * rinv);
            q = fminf(fmaxf(q, -128.f), 127.f) * scale;
            int c  = c0 + j / 9;
            int rs = j % 9;
            // wt2[rs][c>>5][(c>>3)&3][k][c&7]
            int idx = ((((rs * 8 + (c >> 5)) * 4 + ((c >> 3) & 3)) * KOUT) + k) * 8 + (c & 7);
            wt2[idx] = (u16)(__float_as_uint(q) >> 16);
        }
    } else {
        int t = (b - 64) * 256 + threadIdx.x;
        if (t >= NHALO) return;
        int s   = t % 228;
        int ccn = t / 228;
        int cc = ccn & 31, n = ccn >> 5;
        int ph, pw;
        if (s < 58)       { ph = 0;  pw = s; }
        else if (s < 116) { ph = 57; pw = s - 58; }
        else { int r = s - 116; ph = 1 + (r >> 1); pw = (r & 1) * 57; }
        *(uint4*)(xq2 + ((size_t)(n * 32 + cc) * PP + ph * HPAD + pw) * 8) =
            make_uint4(0, 0, 0, 0);
    }
}

// ---------------------------------------------------------------------------
// Implicit-GEMM conv, m97-style: async global_load_lds (16B), both streams
// lane-contiguous (1024 B per wave-instruction). 2-barrier K-loop, BK=32,
// 72 stages (8 cs x 9 taps, cs outer for B L2 locality).
// ---------------------------------------------------------------------------
__global__ __launch_bounds__(256) void conv_kernel(
        const u16* __restrict__ xq2, const u16* __restrict__ wt2,
        const float* __restrict__ bias, float* __restrict__ out) {
    __shared__ u16 lA[4096];   // [kc(4)][kout row(128)][8]
    __shared__ u16 lB[4096];   // [kc(4)][col(128)][8]

    const int tid  = threadIdx.x;
    const int lane = tid & 63;
    const int wv   = tid >> 6;
    const int bx   = blockIdx.x;
    const int n    = bx / TILES;
    const int t0   = (bx % TILES) * 128;
    const int k0   = blockIdx.y * 128;

    // per-lane global half-index bases (lane stride = 8 halves = 16 B)
    const int aLane = (wv * KOUT + k0 + lane) * 8;             // + (rs*8+cs)*8192 + i*512
    const int bLane = ((n * 32 + wv) * PP + t0 + lane) * 8;    // + cs*107648 + (xoff + i*64)*8

    const int frow = lane & 15;
    const int fkk  = lane >> 4;
    const u16* fA = lA + fkk * 1024 + ((wv >> 1) * 64 + frow) * 8;
    const u16* fB = lB + fkk * 1024 + ((wv & 1) * 64 + frow) * 8;

    f32x4 acc[4][4] = {};

    for (int cs = 0; cs < 8; cs++) {
        for (int rs = 0; rs < 9; rs++) {
            const int xoff = (rs / 3) * HPAD + (rs % 3);
            const int aIdx = aLane + (rs * 8 + cs) * 8192;
            const int bI0  = bLane + cs * 107648 + xoff * 8;
            __syncthreads();                       // prior stage's frag reads done
#pragma unroll
            for (int i = 0; i < 2; i++)
                __builtin_amdgcn_global_load_lds(
                    (glb_u32_t*)(wt2 + aIdx + i * 512),
                    (lds_u32_t*)(lA + wv * 1024 + i * 512), 16, 0, 0);
#pragma unroll
            for (int i = 0; i < 2; i++) {
                int idx = bI0 + i * 512;
                idx = min(idx, MAXB);              // tail lanes gather in-bounds garbage
                __builtin_amdgcn_global_load_lds(
                    (glb_u32_t*)(xq2 + idx),
                    (lds_u32_t*)(lB + wv * 1024 + i * 512), 16, 0, 0);
            }
            __syncthreads();                       // vmcnt drained at barrier
            short8 af[4], bf[4];
#pragma unroll
            for (int i = 0; i < 4; i++) af[i] = *(const short8*)(fA + i * 128);
#pragma unroll
            for (int j = 0; j < 4; j++) bf[j] = *(const short8*)(fB + j * 128);
#pragma unroll
            for (int i = 0; i < 4; i++)
#pragma unroll
                for (int j = 0; j < 4; j++)
                    acc[i][j] = __builtin_amdgcn_mfma_f32_16x16x32_bf16(
                        af[i], bf[j], acc[i][j], 0, 0, 0);
        }
    }

    // epilogue: rows = outch, cols = padded pixel t0+col; skip invalid cols
    const int kbase = k0 + (wv >> 1) * 64 + fkk * 4;
    const int mbase = (wv & 1) * 64 + frow;
#pragma unroll
    for (int j = 0; j < 4; j++) {
        int ppp = t0 + mbase + j * 16;
        int h = ppp / HPAD, w = ppp % HPAD;
        if (w < WIMG && h < HIMG) {
            float* ob = out + (size_t)n * KOUT * PIX + h * WIMG + w;
#pragma unroll
            for (int i = 0; i < 4; i++) {
                int kch = kbase + i * 16;
#pragma unroll
                for (int r = 0; r < 4; r++)
                    ob[(size_t)(kch + r) * PIX] = acc[i][j][r] + bias[kch + r];
            }
        }
    }
}

// ---------------------------------------------------------------------------
extern "C" void kernel_launch(void* const* d_in, const int* in_sizes, int n_in,
                              void* d_out, int out_size, void* d_ws, size_t ws_size,
                              hipStream_t stream) {
    const float* x   = (const float*)d_in[0];
    const float* wgt = (const float*)d_in[1];
    const float* bs  = (const float*)d_in[2];
    float* out = (float*)d_out;

    u16* xq2 = (u16*)d_ws;                 // 27.56 MB chunked padded activations
    u16* wt2 = xq2 + XQ_HALVES;            // 1.18 MB  staged weight layout
    u16* qn  = wt2 + NWEL;                 // 25.69 MB NCHW bf16 intermediate

    quant_x_nchw<<<(NGX + 255) / 256, 256, 0, stream>>>(x, qn);
    quant_w_halo<<<64 + (NHALO + 255) / 256, 256, 0, stream>>>(wgt, wt2, xq2);
    transpose_x<<<dim3(PIX / 64, CIN / 64, NIMG), 256, 0, stream>>>(qn, xq2);
    conv_kernel<<<dim3(NIMG * TILES, 2), 256, 0, stream>>>(xq2, wt2, bs, out);
}